// Round 10
// baseline (3868.422 us; speedup 1.0000x reference)
//
#include <hip/hip_runtime.h>
#include <hip/hip_bf16.h>

typedef __attribute__((ext_vector_type(8))) short bf16x8;
typedef __attribute__((ext_vector_type(4))) float f32x4;

__device__ __forceinline__ float bf2f(unsigned short u) {
    union { unsigned int i; float f; } v; v.i = ((unsigned int)u) << 16; return v.f;
}
__device__ __forceinline__ unsigned short f2bf(float f) {
    union { float f; unsigned int i; } v; v.f = f;
    unsigned int x = v.i;
    return (unsigned short)((x + 0x7FFFu + ((x >> 16) & 1u)) >> 16);
}

__device__ __forceinline__ void gload_lds16(const unsigned short* g, unsigned short* l) {
    __builtin_amdgcn_global_load_lds(
        (const __attribute__((address_space(1))) unsigned int*)g,
        (__attribute__((address_space(3))) unsigned int*)l,
        16, 0, 0);
}

#define VM0  asm volatile("s_waitcnt vmcnt(0)" ::: "memory")
#define SB0  __builtin_amdgcn_sched_barrier(0)

// ---------------------------------------------------------------------------
// concat(motion, command) -> bf16 [8192, 576]
// ---------------------------------------------------------------------------
__global__ void concat_cvt(const float* __restrict__ motion,
                           const float* __restrict__ command,
                           unsigned short* __restrict__ out) {
    int id = blockIdx.x * 256 + threadIdx.x;
    int b = id / 144, q = id % 144;
    float4 v;
    if (q < 128) v = *(const float4*)(motion + (size_t)b * 512 + q * 4);
    else         v = *(const float4*)(command + (size_t)b * 64 + (q - 128) * 4);
    ushort4 o;
    o.x = f2bf(v.x); o.y = f2bf(v.y); o.z = f2bf(v.z); o.w = f2bf(v.w);
    *(ushort4*)(out + (size_t)b * 576 + q * 4) = o;
}

// ---------------------------------------------------------------------------
// batched fp32 [K,N] -> bf16 [N,K] per expert (tpe = 64x64 tiles per expert)
// ---------------------------------------------------------------------------
__global__ void transpose_cvt(const float* __restrict__ in,
                              unsigned short* __restrict__ out,
                              int K, int N, int tpe) {
    __shared__ unsigned short tile[64][72];
    int e = blockIdx.x / tpe, r = blockIdx.x % tpe;
    in  += (size_t)e * K * N;
    out += (size_t)e * N * K;
    int nbn = N / 64;
    int k0 = (r / nbn) * 64;
    int n0 = (r % nbn) * 64;
    int t = threadIdx.x;
    int tx = t & 63, ty = t >> 6;
    #pragma unroll
    for (int rr = 0; rr < 16; ++rr) {
        int kr = ty + rr * 4;
        tile[kr][tx] = f2bf(in[(size_t)(k0 + kr) * N + n0 + tx]);
    }
    __syncthreads();
    int txh = t & 31, tyh = t >> 5;
    #pragma unroll
    for (int rr = 0; rr < 8; ++rr) {
        int nr = tyh + rr * 8;
        unsigned int vlo = tile[2 * txh][nr];
        unsigned int vhi = tile[2 * txh + 1][nr];
        unsigned int* o32 = (unsigned int*)(out + (size_t)(n0 + nr) * K + k0);
        o32[txh] = vlo | (vhi << 16);
    }
}

// ---------------------------------------------------------------------------
// gating final: coeffs = softmax(g2 @ w3 + b3)
// ---------------------------------------------------------------------------
__global__ __launch_bounds__(256) void gating_kernel(
    const unsigned short* __restrict__ g2,
    const float* __restrict__ w3, const float* __restrict__ b3,
    float* __restrict__ coeffs) {
    __shared__ float w3s[8][1024];
    int t = threadIdx.x;
    for (int i = t; i < 1024; i += 256) {
        #pragma unroll
        for (int e = 0; e < 8; ++e) w3s[e][i] = w3[(size_t)i * 8 + e];
    }
    __syncthreads();
    int lane = t & 63, wv = t >> 6;
    int row = blockIdx.x * 4 + wv;
    const unsigned short* xr = g2 + (size_t)row * 1024;
    float acc[8];
    #pragma unroll
    for (int e = 0; e < 8; ++e) acc[e] = 0.f;
    for (int it = 0; it < 16; ++it) {
        float xv = bf2f(xr[lane + it * 64]);
        #pragma unroll
        for (int e = 0; e < 8; ++e) acc[e] += xv * w3s[e][lane + it * 64];
    }
    #pragma unroll
    for (int e = 0; e < 8; ++e) {
        float v = acc[e];
        #pragma unroll
        for (int off = 32; off; off >>= 1) v += __shfl_xor(v, off);
        acc[e] = v + b3[e];
    }
    float mx = acc[0];
    #pragma unroll
    for (int e = 1; e < 8; ++e) mx = fmaxf(mx, acc[e]);
    float s = 0.f;
    #pragma unroll
    for (int e = 0; e < 8; ++e) { acc[e] = __expf(acc[e] - mx); s += acc[e]; }
    float inv = 1.f / s;
    if (lane < 8) coeffs[(size_t)row * 8 + lane] = acc[lane] * inv;
}

// ---------------------------------------------------------------------------
// gating GEMM (proven): 128x128x64, global_load_lds both operands, 4 blk/CU
// ---------------------------------------------------------------------------
template<bool DO_ELU>
__global__ __launch_bounds__(256, 4)
void gemm_bf16(const unsigned short* __restrict__ A,
               const unsigned short* __restrict__ BT,
               const float* __restrict__ bias,
               unsigned short* __restrict__ Out,
               int N, int ld, int kpart) {
    __shared__ unsigned short As[128 * 64];
    __shared__ unsigned short Bs[128 * 64];
    int ntn = N >> 7;
    int nwg = gridDim.x;
    int bid = blockIdx.x;
    { int cpx = nwg >> 3; bid = (bid & 7) * cpx + (bid >> 3); }
    int tm = bid / ntn, tn = bid - tm * ntn;
    int row0 = tm << 7, col0 = tn << 7;
    int t = threadIdx.x;
    int lane = t & 63;
    int wid = t >> 6;
    int wr = wid >> 1, wc = wid & 1;
    const unsigned short* Ab = A + (size_t)(row0 + wid * 32 + (lane >> 3)) * ld + (lane & 7) * 8;
    const unsigned short* Bb = BT + (size_t)(col0 + wid * 32 + (lane >> 3)) * ld + (lane & 7) * 8;
    unsigned short* Asd = &As[wid * 32 * 64];
    unsigned short* Bsd = &Bs[wid * 32 * 64];
    f32x4 acc[4][4];
    #pragma unroll
    for (int i = 0; i < 4; ++i)
        #pragma unroll
        for (int j = 0; j < 4; ++j) acc[i][j] = (f32x4){0.f, 0.f, 0.f, 0.f};
    int nkt = kpart >> 6;
    for (int kt = 0; kt < nkt; ++kt) {
        size_t ko = (size_t)kt << 6;
        #pragma unroll
        for (int q = 0; q < 4; ++q) {
            gload_lds16(Ab + (size_t)(q * 8) * ld + ko, Asd + q * 8 * 64);
            gload_lds16(Bb + (size_t)(q * 8) * ld + ko, Bsd + q * 8 * 64);
        }
        __syncthreads();
        #pragma unroll
        for (int kk = 0; kk < 2; ++kk) {
            bf16x8 af[4], bfr[4];
            #pragma unroll
            for (int m = 0; m < 4; ++m)
                af[m] = *(const bf16x8*)(&As[(wr * 64 + m * 16 + (lane & 15)) * 64 + kk * 32 + (lane >> 4) * 8]);
            #pragma unroll
            for (int n = 0; n < 4; ++n)
                bfr[n] = *(const bf16x8*)(&Bs[(wc * 64 + n * 16 + (lane & 15)) * 64 + kk * 32 + (lane >> 4) * 8]);
            #pragma unroll
            for (int m = 0; m < 4; ++m)
                #pragma unroll
                for (int n = 0; n < 4; ++n)
                    acc[m][n] = __builtin_amdgcn_mfma_f32_16x16x32_bf16(af[m], bfr[n], acc[m][n], 0, 0, 0);
        }
        __syncthreads();
    }
    #pragma unroll
    for (int m = 0; m < 4; ++m) {
        int rbase = row0 + wr * 64 + m * 16 + ((lane >> 4) << 2);
        #pragma unroll
        for (int n = 0; n < 4; ++n) {
            int cg = col0 + wc * 64 + n * 16 + (lane & 15);
            float bv = bias[cg];
            #pragma unroll
            for (int r2 = 0; r2 < 4; ++r2) {
                float v = acc[m][n][r2] + bv;
                if (DO_ELU) v = v > 0.f ? v : (__expf(v) - 1.f);
                Out[(size_t)(rbase + r2) * N + cg] = f2bf(v);
            }
        }
    }
}

// ---------------------------------------------------------------------------
// Fused MoE GEMM v3: 128x256-virtual tile, 4 waves (wave = 128x64v), BK=32,
// ring-2 LDS (48 KB -> 3 blocks/CU), stage-1-ahead + VM0 + single barrier
// (TLP across 3 resident blocks hides the drain). Swizzled staging/reads,
// swapped-operand MFMA. Virtual cols: vc = e*32 + j.
// Epilogue: in-register expert mix -> LDS fp32 partials (2 row-half passes,
// 32 KB) -> cross-wave sum + bias/ELU -> direct y store.
// ---------------------------------------------------------------------------
template<bool DO_ELU, bool OUT_F32>
__global__ __launch_bounds__(256, 3)
void gemm_fused(const unsigned short* __restrict__ A,   // [8192, K]
                const unsigned short* __restrict__ BT,  // [8*dout, K]
                const float* __restrict__ coeffs,       // [8192, 8]
                const float* __restrict__ bias,         // [8*dout]
                void* __restrict__ Out,                 // [8192, dout]
                int K, int dout) {
    __shared__ unsigned short lds[24576];            // 2 slots x (A 4096 + B 8192) = 48 KB

    int ntn = dout >> 5;
    int nwg = gridDim.x;
    int bid = blockIdx.x;
    { int cpx = nwg >> 3; bid = (bid & 7) * cpx + (bid >> 3); }
    int tm = bid / ntn, tn = bid - tm * ntn;
    int row0 = tm << 7;                              // 128-row tile
    int c0 = tn << 5;                                // output col base
    int nkt = K >> 5;

    int t = threadIdx.x;
    int lane = t & 63, wn = t >> 6;                  // 4 waves = wn 0..3
    int q = lane >> 4;
    int l15 = lane & 15;

    // fragment ds_read offsets (ushort units), swizzled within 64B rows
    int aoff[8], boff[4];
    #pragma unroll
    for (int m = 0; m < 8; ++m) {
        int row = m * 16 + l15;
        aoff[m] = row * 32 + ((q ^ ((row >> 1) & 3)) << 3);
    }
    #pragma unroll
    for (int n = 0; n < 4; ++n) {
        int vr = wn * 64 + n * 16 + l15;
        boff[n] = 4096 + vr * 32 + ((q ^ ((vr >> 1) & 3)) << 3);
    }

    // staging sources (per-thread, inverse-swizzled column)
    int br = wn * 16 + (lane >> 2);                  // base row 0..63
    int sg = ((lane & 3) ^ ((br >> 1) & 3)) * 8;     // source col (ushorts)
    const unsigned short* Asrc0 = A + (size_t)(row0 + br) * K + sg;
    const unsigned short* Asrc1 = Asrc0 + (size_t)64 * K;
    int hb = br >> 5, lb = br & 31;
    const unsigned short* Bs0 = BT + (size_t)((0 + hb) * dout + c0 + lb) * K + sg;
    const unsigned short* Bs1 = BT + (size_t)((2 + hb) * dout + c0 + lb) * K + sg;
    const unsigned short* Bs2 = BT + (size_t)((4 + hb) * dout + c0 + lb) * K + sg;
    const unsigned short* Bs3 = BT + (size_t)((6 + hb) * dout + c0 + lb) * K + sg;
    int wd = wn * 512;                               // wave-uniform dest term (ushorts)

    f32x4 acc[8][4];
    #pragma unroll
    for (int m = 0; m < 8; ++m)
        #pragma unroll
        for (int n = 0; n < 4; ++n) acc[m][n] = (f32x4){0.f, 0.f, 0.f, 0.f};

    // ---- prologue: stage slot 0 ----
    gload_lds16(Asrc0, &lds[wd]);
    gload_lds16(Asrc1, &lds[2048 + wd]);
    gload_lds16(Bs0,   &lds[4096 + wd]);
    gload_lds16(Bs1,   &lds[6144 + wd]);
    gload_lds16(Bs2,   &lds[8192 + wd]);
    gload_lds16(Bs3,   &lds[10240 + wd]);
    VM0; SB0;
    __builtin_amdgcn_s_barrier();

    for (int s = 0; s < nkt; ++s) {
        int sb = (s & 1) * 12288;
        int rb = ((s + 1) & 1) * 12288;
        int ko = (s + 1) << 5;                       // ushort col offset of slot s+1

        if (s + 1 < nkt) {                           // stage s+1 (buf read at s-1: safe)
            gload_lds16(Asrc0 + ko, &lds[rb + wd]);
            gload_lds16(Asrc1 + ko, &lds[rb + 2048 + wd]);
            gload_lds16(Bs0 + ko,   &lds[rb + 4096 + wd]);
            gload_lds16(Bs1 + ko,   &lds[rb + 6144 + wd]);
            gload_lds16(Bs2 + ko,   &lds[rb + 8192 + wd]);
            gload_lds16(Bs3 + ko,   &lds[rb + 10240 + wd]);
        }
        SB0;

        bf16x8 bfrg[4], afr[8];
        #pragma unroll
        for (int n = 0; n < 4; ++n)
            bfrg[n] = *(const bf16x8*)(&lds[sb + boff[n]]);
        #pragma unroll
        for (int m = 0; m < 8; ++m)
            afr[m] = *(const bf16x8*)(&lds[sb + aoff[m]]);
        __builtin_amdgcn_s_setprio(1);
        #pragma unroll
        for (int m = 0; m < 8; ++m)
            #pragma unroll
            for (int n = 0; n < 4; ++n)
                acc[m][n] = __builtin_amdgcn_mfma_f32_16x16x32_bf16(bfrg[n], afr[m], acc[m][n], 0, 0, 0);
        __builtin_amdgcn_s_setprio(0);
        SB0;
        VM0;                                         // drain s+1 loads (TLP hides)
        SB0;
        __builtin_amdgcn_s_barrier();
    }

    // ======== epilogue ========
    // acc[m][n][r]: row = row0 + m*16 + l15; vc = wn*64 + n*16 + q*4 + r;
    //   e = 2wn + (n>>1); j = (n&1)*16 + q*4 + r; chunk = (n&1)*4 + q.
    int e0 = 2 * wn, e1 = e0 + 1;
    f32x4 b0h[2], b1h[2];
    #pragma unroll
    for (int h = 0; h < 2; ++h) {
        float4 u0 = *(const float4*)(bias + e0 * dout + c0 + h * 16 + q * 4);
        float4 u1 = *(const float4*)(bias + e1 * dout + c0 + h * 16 + q * 4);
        b0h[h] = (f32x4){u0.x, u0.y, u0.z, u0.w};
        b1h[h] = (f32x4){u1.x, u1.y, u1.z, u1.w};
    }
    float* plds = (float*)lds;                       // 4 regions x [64][32] f32 = 32 KB
    __syncthreads();
    #pragma unroll
    for (int p = 0; p < 2; ++p) {
        // phase 1: mix experts for m-frags p*4..p*4+3 -> fp32 partials
        float* preg = plds + (wn << 11);
        #pragma unroll
        for (int mm = 0; mm < 4; ++mm) {
            int rl = mm * 16 + l15;                  // 0..63
            int grow = row0 + p * 64 + rl;
            float ca = coeffs[(size_t)grow * 8 + e0];
            float cb = coeffs[(size_t)grow * 8 + e1];
            #pragma unroll
            for (int h = 0; h < 2; ++h) {
                f32x4 z0 = acc[p * 4 + mm][h];
                f32x4 z1 = acc[p * 4 + mm][h + 2];
                f32x4 pv;
                #pragma unroll
                for (int r = 0; r < 4; ++r)
                    pv[r] = ca * (z0[r] + b0h[h][r]) + cb * (z1[r] + b1h[h][r]);
                int slot = (h * 4 + q) ^ (rl & 7);
                *(f32x4*)(preg + rl * 32 + (slot << 2)) = pv;
            }
        }
        __syncthreads();
        // phase 2: sum 4 wave-partials, act, store 64 rows x 32 cols
        {
            int rr = t >> 2, ch = t & 3;
            size_t obase = (size_t)(row0 + p * 64 + rr) * dout + c0;
            #pragma unroll
            for (int li = 0; li < 2; ++li) {
                int L = ch + li * 4;
                int phys = L ^ (rr & 7);
                f32x4 sum = (f32x4){0.f, 0.f, 0.f, 0.f};
                #pragma unroll
                for (int w2 = 0; w2 < 4; ++w2) {
                    const f32x4 v = *(const f32x4*)(plds + (w2 << 11) + rr * 32 + (phys << 2));
                    sum[0] += v[0]; sum[1] += v[1]; sum[2] += v[2]; sum[3] += v[3];
                }
                if (DO_ELU) {
                    #pragma unroll
                    for (int r = 0; r < 4; ++r)
                        sum[r] = sum[r] > 0.f ? sum[r] : (__expf(sum[r]) - 1.f);
                }
                if (OUT_F32) {
                    float4 o = {sum[0], sum[1], sum[2], sum[3]};
                    *(float4*)((float*)Out + obase + L * 4) = o;
                } else {
                    ushort4 o;
                    o.x = f2bf(sum[0]); o.y = f2bf(sum[1]);
                    o.z = f2bf(sum[2]); o.w = f2bf(sum[3]);
                    *(ushort4*)((unsigned short*)Out + obase + L * 4) = o;
                }
            }
        }
        __syncthreads();
    }
}

// ---------------------------------------------------------------------------
extern "C" void kernel_launch(void* const* d_in, const int* in_sizes, int n_in,
                              void* d_out, int out_size, void* d_ws, size_t ws_size,
                              hipStream_t stream) {
    const float* motion  = (const float*)d_in[0];
    const float* command = (const float*)d_in[1];
    const float* g_w1 = (const float*)d_in[2];
    const float* g_b1 = (const float*)d_in[3];
    const float* g_w2 = (const float*)d_in[4];
    const float* g_b2 = (const float*)d_in[5];
    const float* g_w3 = (const float*)d_in[6];
    const float* g_b3 = (const float*)d_in[7];
    const float* w[6]  = {(const float*)d_in[8],  (const float*)d_in[10],
                          (const float*)d_in[12], (const float*)d_in[14],
                          (const float*)d_in[16], (const float*)d_in[18]};
    const float* bb[6] = {(const float*)d_in[9],  (const float*)d_in[11],
                          (const float*)d_in[13], (const float*)d_in[15],
                          (const float*)d_in[17], (const float*)d_in[19]};

    char* ws = (char*)d_ws;
    unsigned short* xc0  = (unsigned short*)ws;                 //  9,437,184
    unsigned short* actA = (unsigned short*)(ws + 9437184);     // 16,777,216
    unsigned short* actB = (unsigned short*)(ws + 26214400);    // 16,777,216
    float* coeffs        = (float*)(ws + 42991616);             //    262,144
    unsigned short* wT   = (unsigned short*)(ws + 43253760);    // 16,777,216

    // 1. concat + convert input
    concat_cvt<<<4608, 256, 0, stream>>>(motion, command, xc0);

    // 2. gating network
    transpose_cvt<<<144, 256, 0, stream>>>(g_w1, wT, 576, 1024, 144);
    gemm_bf16<true><<<512, 256, 0, stream>>>(xc0, wT, g_b1, actA, 1024, 576, 576);
    transpose_cvt<<<256, 256, 0, stream>>>(g_w2, wT, 1024, 1024, 256);
    gemm_bf16<true><<<512, 256, 0, stream>>>(actA, wT, g_b2, actB, 1024, 1024, 1024);
    gating_kernel<<<2048, 256, 0, stream>>>(actB, g_w3, g_b3, coeffs);

    // 3. MoE layer 0: K=576, dout=1024 -> actA  (grid 64tm x 32tn = 2048)
    transpose_cvt<<<1152, 256, 0, stream>>>(w[0], wT, 576, 1024, 144);
    gemm_fused<true, false><<<2048, 256, 0, stream>>>(
        xc0, wT, coeffs, bb[0], actA, 576, 1024);

    // 4. MoE layers 1..4: K=1024, dout=1024, ping-pong actA/actB
    unsigned short* bufs[2] = {actA, actB};
    for (int l = 1; l <= 4; ++l) {
        unsigned short* in  = bufs[(l + 1) & 1];
        unsigned short* out = bufs[l & 1];
        transpose_cvt<<<2048, 256, 0, stream>>>(w[l], wT, 1024, 1024, 256);
        gemm_fused<true, false><<<2048, 256, 0, stream>>>(
            in, wT, coeffs, bb[l], out, 1024, 1024);
    }

    // 5. MoE layer 5: K=1024, dout=512, fp32 out (grid 64tm x 16tn = 1024)
    transpose_cvt<<<1024, 256, 0, stream>>>(w[5], wT, 1024, 512, 128);
    gemm_fused<false, true><<<1024, 256, 0, stream>>>(
        actA, wT, coeffs, bb[5], d_out, 1024, 512);
}

// Round 11
// 793.747 us; speedup vs baseline: 4.8736x; 4.8736x over previous
//
#include <hip/hip_runtime.h>
#include <hip/hip_bf16.h>

typedef __attribute__((ext_vector_type(8))) short bf16x8;
typedef __attribute__((ext_vector_type(4))) float f32x4;

__device__ __forceinline__ float bf2f(unsigned short u) {
    union { unsigned int i; float f; } v; v.i = ((unsigned int)u) << 16; return v.f;
}
__device__ __forceinline__ unsigned short f2bf(float f) {
    union { float f; unsigned int i; } v; v.f = f;
    unsigned int x = v.i;
    return (unsigned short)((x + 0x7FFFu + ((x >> 16) & 1u)) >> 16);
}

__device__ __forceinline__ void gload_lds16(const unsigned short* g, unsigned short* l) {
    __builtin_amdgcn_global_load_lds(
        (const __attribute__((address_space(1))) unsigned int*)g,
        (__attribute__((address_space(3))) unsigned int*)l,
        16, 0, 0);
}

#define VM4  asm volatile("s_waitcnt vmcnt(4)" ::: "memory")
#define VM0  asm volatile("s_waitcnt vmcnt(0)" ::: "memory")
#define LG0  asm volatile("s_waitcnt lgkmcnt(0)" ::: "memory")
#define SB0  __builtin_amdgcn_sched_barrier(0)
#define BAR  __builtin_amdgcn_s_barrier()

// ---------------------------------------------------------------------------
// concat(motion, command) -> bf16 [8192, 576]
// ---------------------------------------------------------------------------
__global__ void concat_cvt(const float* __restrict__ motion,
                           const float* __restrict__ command,
                           unsigned short* __restrict__ out) {
    int id = blockIdx.x * 256 + threadIdx.x;
    int b = id / 144, q = id % 144;
    float4 v;
    if (q < 128) v = *(const float4*)(motion + (size_t)b * 512 + q * 4);
    else         v = *(const float4*)(command + (size_t)b * 64 + (q - 128) * 4);
    ushort4 o;
    o.x = f2bf(v.x); o.y = f2bf(v.y); o.z = f2bf(v.z); o.w = f2bf(v.w);
    *(ushort4*)(out + (size_t)b * 576 + q * 4) = o;
}

// ---------------------------------------------------------------------------
// batched fp32 [K,N] -> bf16 [N,K] per expert (tpe = 64x64 tiles per expert)
// ---------------------------------------------------------------------------
__global__ void transpose_cvt(const float* __restrict__ in,
                              unsigned short* __restrict__ out,
                              int K, int N, int tpe) {
    __shared__ unsigned short tile[64][72];
    int e = blockIdx.x / tpe, r = blockIdx.x % tpe;
    in  += (size_t)e * K * N;
    out += (size_t)e * N * K;
    int nbn = N / 64;
    int k0 = (r / nbn) * 64;
    int n0 = (r % nbn) * 64;
    int t = threadIdx.x;
    int tx = t & 63, ty = t >> 6;
    #pragma unroll
    for (int rr = 0; rr < 16; ++rr) {
        int kr = ty + rr * 4;
        tile[kr][tx] = f2bf(in[(size_t)(k0 + kr) * N + n0 + tx]);
    }
    __syncthreads();
    int txh = t & 31, tyh = t >> 5;
    #pragma unroll
    for (int rr = 0; rr < 8; ++rr) {
        int nr = tyh + rr * 8;
        unsigned int vlo = tile[2 * txh][nr];
        unsigned int vhi = tile[2 * txh + 1][nr];
        unsigned int* o32 = (unsigned int*)(out + (size_t)(n0 + nr) * K + k0);
        o32[txh] = vlo | (vhi << 16);
    }
}

// ---------------------------------------------------------------------------
// gating final: coeffs = softmax(g2 @ w3 + b3)
// ---------------------------------------------------------------------------
__global__ __launch_bounds__(256) void gating_kernel(
    const unsigned short* __restrict__ g2,
    const float* __restrict__ w3, const float* __restrict__ b3,
    float* __restrict__ coeffs) {
    __shared__ float w3s[8][1024];
    int t = threadIdx.x;
    for (int i = t; i < 1024; i += 256) {
        #pragma unroll
        for (int e = 0; e < 8; ++e) w3s[e][i] = w3[(size_t)i * 8 + e];
    }
    __syncthreads();
    int lane = t & 63, wv = t >> 6;
    int row = blockIdx.x * 4 + wv;
    const unsigned short* xr = g2 + (size_t)row * 1024;
    float acc[8];
    #pragma unroll
    for (int e = 0; e < 8; ++e) acc[e] = 0.f;
    for (int it = 0; it < 16; ++it) {
        float xv = bf2f(xr[lane + it * 64]);
        #pragma unroll
        for (int e = 0; e < 8; ++e) acc[e] += xv * w3s[e][lane + it * 64];
    }
    #pragma unroll
    for (int e = 0; e < 8; ++e) {
        float v = acc[e];
        #pragma unroll
        for (int off = 32; off; off >>= 1) v += __shfl_xor(v, off);
        acc[e] = v + b3[e];
    }
    float mx = acc[0];
    #pragma unroll
    for (int e = 1; e < 8; ++e) mx = fmaxf(mx, acc[e]);
    float s = 0.f;
    #pragma unroll
    for (int e = 0; e < 8; ++e) { acc[e] = __expf(acc[e] - mx); s += acc[e]; }
    float inv = 1.f / s;
    if (lane < 8) coeffs[(size_t)row * 8 + lane] = acc[lane] * inv;
}

// ---------------------------------------------------------------------------
// gating GEMM (proven): 128x128x64, global_load_lds both operands, 4 blk/CU
// ---------------------------------------------------------------------------
template<bool DO_ELU>
__global__ __launch_bounds__(256, 4)
void gemm_bf16(const unsigned short* __restrict__ A,
               const unsigned short* __restrict__ BT,
               const float* __restrict__ bias,
               unsigned short* __restrict__ Out,
               int N, int ld, int kpart) {
    __shared__ unsigned short As[128 * 64];
    __shared__ unsigned short Bs[128 * 64];
    int ntn = N >> 7;
    int nwg = gridDim.x;
    int bid = blockIdx.x;
    { int cpx = nwg >> 3; bid = (bid & 7) * cpx + (bid >> 3); }
    int tm = bid / ntn, tn = bid - tm * ntn;
    int row0 = tm << 7, col0 = tn << 7;
    int t = threadIdx.x;
    int lane = t & 63;
    int wid = t >> 6;
    int wr = wid >> 1, wc = wid & 1;
    const unsigned short* Ab = A + (size_t)(row0 + wid * 32 + (lane >> 3)) * ld + (lane & 7) * 8;
    const unsigned short* Bb = BT + (size_t)(col0 + wid * 32 + (lane >> 3)) * ld + (lane & 7) * 8;
    unsigned short* Asd = &As[wid * 32 * 64];
    unsigned short* Bsd = &Bs[wid * 32 * 64];
    f32x4 acc[4][4];
    #pragma unroll
    for (int i = 0; i < 4; ++i)
        #pragma unroll
        for (int j = 0; j < 4; ++j) acc[i][j] = (f32x4){0.f, 0.f, 0.f, 0.f};
    int nkt = kpart >> 6;
    for (int kt = 0; kt < nkt; ++kt) {
        size_t ko = (size_t)kt << 6;
        #pragma unroll
        for (int q = 0; q < 4; ++q) {
            gload_lds16(Ab + (size_t)(q * 8) * ld + ko, Asd + q * 8 * 64);
            gload_lds16(Bb + (size_t)(q * 8) * ld + ko, Bsd + q * 8 * 64);
        }
        __syncthreads();
        #pragma unroll
        for (int kk = 0; kk < 2; ++kk) {
            bf16x8 af[4], bfr[4];
            #pragma unroll
            for (int m = 0; m < 4; ++m)
                af[m] = *(const bf16x8*)(&As[(wr * 64 + m * 16 + (lane & 15)) * 64 + kk * 32 + (lane >> 4) * 8]);
            #pragma unroll
            for (int n = 0; n < 4; ++n)
                bfr[n] = *(const bf16x8*)(&Bs[(wc * 64 + n * 16 + (lane & 15)) * 64 + kk * 32 + (lane >> 4) * 8]);
            #pragma unroll
            for (int m = 0; m < 4; ++m)
                #pragma unroll
                for (int n = 0; n < 4; ++n)
                    acc[m][n] = __builtin_amdgcn_mfma_f32_16x16x32_bf16(af[m], bfr[n], acc[m][n], 0, 0, 0);
        }
        __syncthreads();
    }
    #pragma unroll
    for (int m = 0; m < 4; ++m) {
        int rbase = row0 + wr * 64 + m * 16 + ((lane >> 4) << 2);
        #pragma unroll
        for (int n = 0; n < 4; ++n) {
            int cg = col0 + wc * 64 + n * 16 + (lane & 15);
            float bv = bias[cg];
            #pragma unroll
            for (int r2 = 0; r2 < 4; ++r2) {
                float v = acc[m][n][r2] + bv;
                if (DO_ELU) v = v > 0.f ? v : (__expf(v) - 1.f);
                Out[(size_t)(rbase + r2) * N + cg] = f2bf(v);
            }
        }
    }
}

// ---------------------------------------------------------------------------
// Fused MoE GEMM v4 (m201-style 4-phase/K64 schedule): 256x256-virtual tile,
// 8 waves (2M x 4N, wave = 128x64v), BK=64 tiles, double-buffered LDS
// (2 x 64 KB; regions A-k0/A-k1/B-k0/B-k1 of 16 KB), proven 64B-row swizzle,
// swapped-operand MFMA. Per phase: {ds-read subtile + stage 1 half-tile ->
// s_barrier -> lgkmcnt(0) -> setprio + 16 MFMA -> s_barrier}. vmcnt(4) only
// at phases 2 and 4. Stage order per tile T (into buf T+1): Bk0,Ak0,Bk1,Ak1.
// Epilogue: in-register expert mix -> LDS fp32 partials -> y store (proven).
// ---------------------------------------------------------------------------
template<bool DO_ELU, bool OUT_F32>
__global__ __launch_bounds__(512, 1)
void gemm_fused(const unsigned short* __restrict__ A,   // [8192, K]
                const unsigned short* __restrict__ BT,  // [8*dout, K]
                const float* __restrict__ coeffs,       // [8192, 8]
                const float* __restrict__ bias,         // [8*dout]
                void* __restrict__ Out,                 // [8192, dout]
                int K, int dout) {
    __shared__ unsigned short lds[65536];  // 2 buf x (A 16384 + B 16384) ushorts

    int ntn = dout >> 5;
    int nwg = gridDim.x;
    int bid = blockIdx.x;
    { int cpx = nwg >> 3; bid = (bid & 7) * cpx + (bid >> 3); }
    int tm = bid / ntn, tn = bid - tm * ntn;
    int row0 = tm << 8;
    int c0 = tn << 5;                                // output col base
    int nkt = K >> 6;                                // 64-wide K tiles

    int t = threadIdx.x;
    int lane = t & 63, wid = t >> 6;
    int wm = wid >> 2, wn = wid & 3;                 // 2x4 waves, each 128x64v
    int q = lane >> 4;
    int l15 = lane & 15;

    // fragment ds_read offsets (ushort units, region-relative), swizzled
    int aoff[8], boff[4];
    #pragma unroll
    for (int m = 0; m < 8; ++m) {
        int r = wm * 128 + m * 16 + l15;
        aoff[m] = r * 32 + ((q ^ ((r >> 1) & 3)) << 3);
    }
    #pragma unroll
    for (int n = 0; n < 4; ++n) {
        int vr = wn * 64 + n * 16 + l15;
        boff[n] = 16384 + vr * 32 + ((q ^ ((vr >> 1) & 3)) << 3);
    }

    // staging sources: thread t covers rows r0=t>>2 and r0+128, chunk t&3,
    // inverse-swizzled source column sg
    int r0 = t >> 2;
    int sg = ((t & 3) ^ ((t >> 3) & 3)) * 8;         // source chunk (ushorts)
    const unsigned short* AsrcR0 = A + (size_t)(row0 + r0) * K + sg;
    const unsigned short* AsrcR1 = AsrcR0 + (size_t)128 * K;
    int Bh = r0 >> 5, Blow = r0 & 31;
    const unsigned short* BsrcR0 = BT + ((size_t)(Bh * dout + c0 + Blow)) * K + sg;
    const unsigned short* BsrcR1 = BT + ((size_t)((Bh + 4) * dout + c0 + Blow)) * K + sg;

    f32x4 acc[8][4];
    #pragma unroll
    for (int m = 0; m < 8; ++m)
        #pragma unroll
        for (int n = 0; n < 4; ++n) acc[m][n] = (f32x4){0.f, 0.f, 0.f, 0.f};

    // ---- prologue: stage tile 0 fully into buf 0 (8 loads) ----
    {
        gload_lds16(BsrcR0,      &lds[16384 + t * 8]);
        gload_lds16(BsrcR1,      &lds[16384 + 4096 + t * 8]);
        gload_lds16(AsrcR0,      &lds[t * 8]);
        gload_lds16(AsrcR1,      &lds[4096 + t * 8]);
        gload_lds16(BsrcR0 + 32, &lds[24576 + t * 8]);
        gload_lds16(BsrcR1 + 32, &lds[24576 + 4096 + t * 8]);
        gload_lds16(AsrcR0 + 32, &lds[8192 + t * 8]);
        gload_lds16(AsrcR1 + 32, &lds[8192 + 4096 + t * 8]);
    }
    VM0; SB0;
    BAR;

    for (int T = 0; T < nkt; ++T) {
        int bb = (T & 1) << 15;                      // current buf (ushort off)
        int nb = ((T + 1) & 1) << 15;                // next buf
        bool st = (T + 1) < nkt;
        int ko = (T + 1) << 6;                       // elem col base of next tile

        bf16x8 bfrg[4], afr[4];

        // ======== phase 1: kk0, m0-3 | stage B-k0(T+1) ========
        #pragma unroll
        for (int n = 0; n < 4; ++n)
            bfrg[n] = *(const bf16x8*)(&lds[bb + boff[n]]);
        #pragma unroll
        for (int m = 0; m < 4; ++m)
            afr[m] = *(const bf16x8*)(&lds[bb + aoff[m]]);
        if (st) {
            gload_lds16(BsrcR0 + ko, &lds[nb + 16384 + t * 8]);
            gload_lds16(BsrcR1 + ko, &lds[nb + 16384 + 4096 + t * 8]);
        }
        SB0; BAR;
        LG0; SB0;
        __builtin_amdgcn_s_setprio(1);
        #pragma unroll
        for (int m = 0; m < 4; ++m)
            #pragma unroll
            for (int n = 0; n < 4; ++n)
                acc[m][n] = __builtin_amdgcn_mfma_f32_16x16x32_bf16(bfrg[n], afr[m], acc[m][n], 0, 0, 0);
        __builtin_amdgcn_s_setprio(0);
        SB0; BAR;

        // ======== phase 2: kk0, m4-7 | stage A-k0(T+1) | vmcnt ========
        #pragma unroll
        for (int m = 0; m < 4; ++m)
            afr[m] = *(const bf16x8*)(&lds[bb + aoff[m + 4]]);
        if (st) {
            gload_lds16(AsrcR0 + ko, &lds[nb + t * 8]);
            gload_lds16(AsrcR1 + ko, &lds[nb + 4096 + t * 8]);
        }
        SB0;
        if (st) { VM4; } else { VM0; }               // lands B-k1/A-k1 of T
        SB0; BAR;
        LG0; SB0;
        __builtin_amdgcn_s_setprio(1);
        #pragma unroll
        for (int m = 0; m < 4; ++m)
            #pragma unroll
            for (int n = 0; n < 4; ++n)
                acc[m + 4][n] = __builtin_amdgcn_mfma_f32_16x16x32_bf16(bfrg[n], afr[m], acc[m + 4][n], 0, 0, 0);
        __builtin_amdgcn_s_setprio(0);
        SB0; BAR;

        // ======== phase 3: kk1, m0-3 | stage B-k1(T+1) ========
        #pragma unroll
        for (int n = 0; n < 4; ++n)
            bfrg[n] = *(const bf16x8*)(&lds[bb + 8192 + boff[n]]);
        #pragma unroll
        for (int m = 0; m < 4; ++m)
            afr[m] = *(const bf16x8*)(&lds[bb + 8192 + aoff[m]]);
        if (st) {
            gload_lds16(BsrcR0 + ko + 32, &lds[nb + 24576 + t * 8]);
            gload_lds16(BsrcR1 + ko + 32, &lds[nb + 24576 + 4096 + t * 8]);
        }
        SB0; BAR;
        LG0; SB0;
        __builtin_amdgcn_s_setprio(1);
        #pragma unroll
        for (int m = 0; m < 4; ++m)
            #pragma unroll
            for (int n = 0; n < 4; ++n)
                acc[m][n] = __builtin_amdgcn_mfma_f32_16x16x32_bf16(bfrg[n], afr[m], acc[m][n], 0, 0, 0);
        __builtin_amdgcn_s_setprio(0);
        SB0; BAR;

        // ======== phase 4: kk1, m4-7 | stage A-k1(T+1) | vmcnt ========
        #pragma unroll
        for (int m = 0; m < 4; ++m)
            afr[m] = *(const bf16x8*)(&lds[bb + 8192 + aoff[m + 4]]);
        if (st) {
            gload_lds16(AsrcR0 + ko + 32, &lds[nb + 8192 + t * 8]);
            gload_lds16(AsrcR1 + ko + 32, &lds[nb + 8192 + 4096 + t * 8]);
        }
        SB0;
        if (st) { VM4; } else { VM0; }               // lands B-k0/A-k0 of T+1
        SB0; BAR;
        LG0; SB0;
        __builtin_amdgcn_s_setprio(1);
        #pragma unroll
        for (int m = 0; m < 4; ++m)
            #pragma unroll
            for (int n = 0; n < 4; ++n)
                acc[m + 4][n] = __builtin_amdgcn_mfma_f32_16x16x32_bf16(bfrg[n], afr[m], acc[m + 4][n], 0, 0, 0);
        __builtin_amdgcn_s_setprio(0);
        SB0; BAR;
    }

    // ======== epilogue phase 1: per-wave expert mix -> LDS fp32 partials ===
    // acc[m][n][r]: row = row0 + wm*128 + m*16 + l15;
    //               vc  = wn*64 + n*16 + q*4 + r; e = 2wn + (n>>1);
    //               j   = (n&1)*16 + q*4 + r.
    float* plds = (float*)lds;                       // 8 regions x [128][32] f32
    __syncthreads();                                 // bufs fully consumed
    {
        int e0 = 2 * wn, e1 = e0 + 1;
        f32x4 b0h[2], b1h[2];
        #pragma unroll
        for (int h = 0; h < 2; ++h) {
            float4 u0 = *(const float4*)(bias + e0 * dout + c0 + h * 16 + q * 4);
            float4 u1 = *(const float4*)(bias + e1 * dout + c0 + h * 16 + q * 4);
            b0h[h] = (f32x4){u0.x, u0.y, u0.z, u0.w};
            b1h[h] = (f32x4){u1.x, u1.y, u1.z, u1.w};
        }
        float* preg = plds + (wid << 12);
        #pragma unroll
        for (int m = 0; m < 8; ++m) {
            int grow = row0 + wm * 128 + m * 16 + l15;
            float c8 = coeffs[(size_t)grow * 8 + e0];
            float c9 = coeffs[(size_t)grow * 8 + e1];
            #pragma unroll
            for (int h = 0; h < 2; ++h) {
                f32x4 z0 = acc[m][h];
                f32x4 z1 = acc[m][h + 2];
                f32x4 p;
                #pragma unroll
                for (int r = 0; r < 4; ++r)
                    p[r] = c8 * (z0[r] + b0h[h][r]) + c9 * (z1[r] + b1h[h][r]);
                int row = m * 16 + l15;
                int slot = (h * 4 + q) ^ (row & 7);
                *(f32x4*)(preg + row * 32 + (slot << 2)) = p;
            }
        }
    }
    __syncthreads();

    // ======== epilogue phase 2: sum 4 wn-partials, act, store ==============
    {
        int r2 = t >> 1;                             // tile row 0..255
        int ch = t & 1;                              // col half (16 cols)
        int wmr = r2 >> 7;
        int rr = r2 & 127;
        int sw = rr & 7;
        size_t obase = (size_t)(row0 + r2) * dout + c0 + ch * 16;
        #pragma unroll
        for (int sl = 0; sl < 4; ++sl) {
            int L = ch * 4 + sl;
            int phys = L ^ sw;
            f32x4 sum = (f32x4){0.f, 0.f, 0.f, 0.f};
            #pragma unroll
            for (int w2 = 0; w2 < 4; ++w2) {
                const f32x4 v = *(const f32x4*)(plds + (((wmr << 2) + w2) << 12) + rr * 32 + (phys << 2));
                sum[0] += v[0]; sum[1] += v[1]; sum[2] += v[2]; sum[3] += v[3];
            }
            if (DO_ELU) {
                #pragma unroll
                for (int r = 0; r < 4; ++r)
                    sum[r] = sum[r] > 0.f ? sum[r] : (__expf(sum[r]) - 1.f);
            }
            if (OUT_F32) {
                float4 o = {sum[0], sum[1], sum[2], sum[3]};
                *(float4*)((float*)Out + obase + sl * 4) = o;
            } else {
                ushort4 o;
                o.x = f2bf(sum[0]); o.y = f2bf(sum[1]);
                o.z = f2bf(sum[2]); o.w = f2bf(sum[3]);
                *(ushort4*)((unsigned short*)Out + obase + sl * 4) = o;
            }
        }
    }
}

// ---------------------------------------------------------------------------
extern "C" void kernel_launch(void* const* d_in, const int* in_sizes, int n_in,
                              void* d_out, int out_size, void* d_ws, size_t ws_size,
                              hipStream_t stream) {
    const float* motion  = (const float*)d_in[0];
    const float* command = (const float*)d_in[1];
    const float* g_w1 = (const float*)d_in[2];
    const float* g_b1 = (const float*)d_in[3];
    const float* g_w2 = (const float*)d_in[4];
    const float* g_b2 = (const float*)d_in[5];
    const float* g_w3 = (const float*)d_in[6];
    const float* g_b3 = (const float*)d_in[7];
    const float* w[6]  = {(const float*)d_in[8],  (const float*)d_in[10],
                          (const float*)d_in[12], (const float*)d_in[14],
                          (const float*)d_in[16], (const float*)d_in[18]};
    const float* bb[6] = {(const float*)d_in[9],  (const float*)d_in[11],
                          (const float*)d_in[13], (const float*)d_in[15],
                          (const float*)d_in[17], (const float*)d_in[19]};

    char* ws = (char*)d_ws;
    unsigned short* xc0  = (unsigned short*)ws;                 //  9,437,184
    unsigned short* actA = (unsigned short*)(ws + 9437184);     // 16,777,216
    unsigned short* actB = (unsigned short*)(ws + 26214400);    // 16,777,216
    float* coeffs        = (float*)(ws + 42991616);             //    262,144
    unsigned short* wT   = (unsigned short*)(ws + 43253760);    // 16,777,216

    // 1. concat + convert input
    concat_cvt<<<4608, 256, 0, stream>>>(motion, command, xc0);

    // 2. gating network
    transpose_cvt<<<144, 256, 0, stream>>>(g_w1, wT, 576, 1024, 144);
    gemm_bf16<true><<<512, 256, 0, stream>>>(xc0, wT, g_b1, actA, 1024, 576, 576);
    transpose_cvt<<<256, 256, 0, stream>>>(g_w2, wT, 1024, 1024, 256);
    gemm_bf16<true><<<512, 256, 0, stream>>>(actA, wT, g_b2, actB, 1024, 1024, 1024);
    gating_kernel<<<2048, 256, 0, stream>>>(actB, g_w3, g_b3, coeffs);

    // 3. MoE layer 0: K=576 (9 K-tiles), dout=1024 -> actA
    transpose_cvt<<<1152, 256, 0, stream>>>(w[0], wT, 576, 1024, 144);
    gemm_fused<true, false><<<1024, 512, 0, stream>>>(
        xc0, wT, coeffs, bb[0], actA, 576, 1024);

    // 4. MoE layers 1..4: K=1024 (16 K-tiles), dout=1024, ping-pong actA/actB
    unsigned short* bufs[2] = {actA, actB};
    for (int l = 1; l <= 4; ++l) {
        unsigned short* in  = bufs[(l + 1) & 1];
        unsigned short* out = bufs[l & 1];
        transpose_cvt<<<2048, 256, 0, stream>>>(w[l], wT, 1024, 1024, 256);
        gemm_fused<true, false><<<1024, 512, 0, stream>>>(
            in, wT, coeffs, bb[l], out, 1024, 1024);
    }

    // 5. MoE layer 5: K=1024, dout=512, fp32 out
    transpose_cvt<<<1024, 256, 0, stream>>>(w[5], wT, 1024, 512, 128);
    gemm_fused<false, true><<<512, 512, 0, stream>>>(
        actA, wT, coeffs, bb[5], d_out, 1024, 512);
}

// Round 12
// 736.013 us; speedup vs baseline: 5.2559x; 1.0784x over previous
//
#include <hip/hip_runtime.h>
#include <hip/hip_bf16.h>

typedef __attribute__((ext_vector_type(8))) short bf16x8;
typedef __attribute__((ext_vector_type(4))) float f32x4;

__device__ __forceinline__ float bf2f(unsigned short u) {
    union { unsigned int i; float f; } v; v.i = ((unsigned int)u) << 16; return v.f;
}
__device__ __forceinline__ unsigned short f2bf(float f) {
    union { float f; unsigned int i; } v; v.f = f;
    unsigned int x = v.i;
    return (unsigned short)((x + 0x7FFFu + ((x >> 16) & 1u)) >> 16);
}

__device__ __forceinline__ void gload_lds16(const unsigned short* g, unsigned short* l) {
    __builtin_amdgcn_global_load_lds(
        (const __attribute__((address_space(1))) unsigned int*)g,
        (__attribute__((address_space(3))) unsigned int*)l,
        16, 0, 0);
}

#define VM0  asm volatile("s_waitcnt vmcnt(0)" ::: "memory")
#define SB0  __builtin_amdgcn_sched_barrier(0)
#define BAR  __builtin_amdgcn_s_barrier()

// ---------------------------------------------------------------------------
// concat(motion, command) -> bf16 [8192, 576]
// ---------------------------------------------------------------------------
__global__ void concat_cvt(const float* __restrict__ motion,
                           const float* __restrict__ command,
                           unsigned short* __restrict__ out) {
    int id = blockIdx.x * 256 + threadIdx.x;
    int b = id / 144, q = id % 144;
    float4 v;
    if (q < 128) v = *(const float4*)(motion + (size_t)b * 512 + q * 4);
    else         v = *(const float4*)(command + (size_t)b * 64 + (q - 128) * 4);
    ushort4 o;
    o.x = f2bf(v.x); o.y = f2bf(v.y); o.z = f2bf(v.z); o.w = f2bf(v.w);
    *(ushort4*)(out + (size_t)b * 576 + q * 4) = o;
}

// ---------------------------------------------------------------------------
// batched fp32 [K,N] -> bf16 [N,K] per expert (tpe = 64x64 tiles per expert)
// ---------------------------------------------------------------------------
__global__ void transpose_cvt(const float* __restrict__ in,
                              unsigned short* __restrict__ out,
                              int K, int N, int tpe) {
    __shared__ unsigned short tile[64][72];
    int e = blockIdx.x / tpe, r = blockIdx.x % tpe;
    in  += (size_t)e * K * N;
    out += (size_t)e * N * K;
    int nbn = N / 64;
    int k0 = (r / nbn) * 64;
    int n0 = (r % nbn) * 64;
    int t = threadIdx.x;
    int tx = t & 63, ty = t >> 6;
    #pragma unroll
    for (int rr = 0; rr < 16; ++rr) {
        int kr = ty + rr * 4;
        tile[kr][tx] = f2bf(in[(size_t)(k0 + kr) * N + n0 + tx]);
    }
    __syncthreads();
    int txh = t & 31, tyh = t >> 5;
    #pragma unroll
    for (int rr = 0; rr < 8; ++rr) {
        int nr = tyh + rr * 8;
        unsigned int vlo = tile[2 * txh][nr];
        unsigned int vhi = tile[2 * txh + 1][nr];
        unsigned int* o32 = (unsigned int*)(out + (size_t)(n0 + nr) * K + k0);
        o32[txh] = vlo | (vhi << 16);
    }
}

// ---------------------------------------------------------------------------
// gating final: coeffs = softmax(g2 @ w3 + b3)
// ---------------------------------------------------------------------------
__global__ __launch_bounds__(256) void gating_kernel(
    const unsigned short* __restrict__ g2,
    const float* __restrict__ w3, const float* __restrict__ b3,
    float* __restrict__ coeffs) {
    __shared__ float w3s[8][1024];
    int t = threadIdx.x;
    for (int i = t; i < 1024; i += 256) {
        #pragma unroll
        for (int e = 0; e < 8; ++e) w3s[e][i] = w3[(size_t)i * 8 + e];
    }
    __syncthreads();
    int lane = t & 63, wv = t >> 6;
    int row = blockIdx.x * 4 + wv;
    const unsigned short* xr = g2 + (size_t)row * 1024;
    float acc[8];
    #pragma unroll
    for (int e = 0; e < 8; ++e) acc[e] = 0.f;
    for (int it = 0; it < 16; ++it) {
        float xv = bf2f(xr[lane + it * 64]);
        #pragma unroll
        for (int e = 0; e < 8; ++e) acc[e] += xv * w3s[e][lane + it * 64];
    }
    #pragma unroll
    for (int e = 0; e < 8; ++e) {
        float v = acc[e];
        #pragma unroll
        for (int off = 32; off; off >>= 1) v += __shfl_xor(v, off);
        acc[e] = v + b3[e];
    }
    float mx = acc[0];
    #pragma unroll
    for (int e = 1; e < 8; ++e) mx = fmaxf(mx, acc[e]);
    float s = 0.f;
    #pragma unroll
    for (int e = 0; e < 8; ++e) { acc[e] = __expf(acc[e] - mx); s += acc[e]; }
    float inv = 1.f / s;
    if (lane < 8) coeffs[(size_t)row * 8 + lane] = acc[lane] * inv;
}

// ---------------------------------------------------------------------------
// gating GEMM (proven): 128x128x64, global_load_lds both operands, 4 blk/CU
// ---------------------------------------------------------------------------
template<bool DO_ELU>
__global__ __launch_bounds__(256, 4)
void gemm_bf16(const unsigned short* __restrict__ A,
               const unsigned short* __restrict__ BT,
               const float* __restrict__ bias,
               unsigned short* __restrict__ Out,
               int N, int ld, int kpart) {
    __shared__ unsigned short As[128 * 64];
    __shared__ unsigned short Bs[128 * 64];
    int ntn = N >> 7;
    int nwg = gridDim.x;
    int bid = blockIdx.x;
    { int cpx = nwg >> 3; bid = (bid & 7) * cpx + (bid >> 3); }
    int tm = bid / ntn, tn = bid - tm * ntn;
    int row0 = tm << 7, col0 = tn << 7;
    int t = threadIdx.x;
    int lane = t & 63;
    int wid = t >> 6;
    int wr = wid >> 1, wc = wid & 1;
    const unsigned short* Ab = A + (size_t)(row0 + wid * 32 + (lane >> 3)) * ld + (lane & 7) * 8;
    const unsigned short* Bb = BT + (size_t)(col0 + wid * 32 + (lane >> 3)) * ld + (lane & 7) * 8;
    unsigned short* Asd = &As[wid * 32 * 64];
    unsigned short* Bsd = &Bs[wid * 32 * 64];
    f32x4 acc[4][4];
    #pragma unroll
    for (int i = 0; i < 4; ++i)
        #pragma unroll
        for (int j = 0; j < 4; ++j) acc[i][j] = (f32x4){0.f, 0.f, 0.f, 0.f};
    int nkt = kpart >> 6;
    for (int kt = 0; kt < nkt; ++kt) {
        size_t ko = (size_t)kt << 6;
        #pragma unroll
        for (int q = 0; q < 4; ++q) {
            gload_lds16(Ab + (size_t)(q * 8) * ld + ko, Asd + q * 8 * 64);
            gload_lds16(Bb + (size_t)(q * 8) * ld + ko, Bsd + q * 8 * 64);
        }
        __syncthreads();
        #pragma unroll
        for (int kk = 0; kk < 2; ++kk) {
            bf16x8 af[4], bfr[4];
            #pragma unroll
            for (int m = 0; m < 4; ++m)
                af[m] = *(const bf16x8*)(&As[(wr * 64 + m * 16 + (lane & 15)) * 64 + kk * 32 + (lane >> 4) * 8]);
            #pragma unroll
            for (int n = 0; n < 4; ++n)
                bfr[n] = *(const bf16x8*)(&Bs[(wc * 64 + n * 16 + (lane & 15)) * 64 + kk * 32 + (lane >> 4) * 8]);
            #pragma unroll
            for (int m = 0; m < 4; ++m)
                #pragma unroll
                for (int n = 0; n < 4; ++n)
                    acc[m][n] = __builtin_amdgcn_mfma_f32_16x16x32_bf16(af[m], bfr[n], acc[m][n], 0, 0, 0);
        }
        __syncthreads();
    }
    #pragma unroll
    for (int m = 0; m < 4; ++m) {
        int rbase = row0 + wr * 64 + m * 16 + ((lane >> 4) << 2);
        #pragma unroll
        for (int n = 0; n < 4; ++n) {
            int cg = col0 + wc * 64 + n * 16 + (lane & 15);
            float bv = bias[cg];
            #pragma unroll
            for (int r2 = 0; r2 < 4; ++r2) {
                float v = acc[m][n][r2] + bv;
                if (DO_ELU) v = v > 0.f ? v : (__expf(v) - 1.f);
                Out[(size_t)(rbase + r2) * N + cg] = f2bf(v);
            }
        }
    }
}

// ---------------------------------------------------------------------------
// Fused MoE GEMM (r9 base + 2D XCD map + 2-slot iterations): 256x256-virtual
// tile, 8 waves (wave = 128x64v), BK=32 slots, 4-slot LDS ring (128 KB),
// swizzled staging/reads, swapped-operand MFMA. Per iteration (2 slots):
// VM0 -> barrier -> stage slots s+2,s+3 (8 loads) -> reads+MFMA (s) ->
// reads+MFMA (s+1). One barrier + one vmcnt per 64 MFMAs.
// XCD map: XCD x owns tm in [4x,4x+4); sequences 4tn-wide chunks so the
// ~32 concurrent blocks/XCD span 4tm x 8tn (6 MB working set vs 18 MB).
// Epilogue: in-register expert mix -> LDS fp32 partials -> y store direct.
// ---------------------------------------------------------------------------
template<bool DO_ELU, bool OUT_F32>
__global__ __launch_bounds__(512, 1)
void gemm_fused(const unsigned short* __restrict__ A,   // [8192, K]
                const unsigned short* __restrict__ BT,  // [8*dout, K]
                const float* __restrict__ coeffs,       // [8192, 8]
                const float* __restrict__ bias,         // [8*dout]
                void* __restrict__ Out,                 // [8192, dout]
                int K, int dout) {
    __shared__ unsigned short lds[65536];           // 4 x (A 8192 + B 8192)

    // 2D concurrency-aware XCD mapping (bijective for nwg = 128*ntn/4... our grids)
    int bid = blockIdx.x;
    int x = bid & 7;                                 // XCD (round-robin dispatch)
    int i = bid >> 3;                                // per-XCD sequence index
    int within = i & 15;
    int tm = x * 4 + (within & 3);
    int tn = (i >> 4) * 4 + (within >> 2);
    int row0 = tm << 8;
    int c0 = tn << 5;                                // output col base
    int nkt = K >> 5;

    int t = threadIdx.x;
    int lane = t & 63, wid = t >> 6;
    int wm = wid >> 2, wn = wid & 3;                 // 2x4 waves, each 128x64
    int q = lane >> 4;
    int l15 = lane & 15;

    // fragment ds_read offsets (ushort units), swizzled
    int aoff[8], boff[4];
    #pragma unroll
    for (int m = 0; m < 8; ++m) {
        int row = wm * 128 + m * 16 + l15;
        aoff[m] = row * 32 + ((q ^ ((row >> 1) & 3)) << 3);
    }
    #pragma unroll
    for (int n = 0; n < 4; ++n) {
        int row = wn * 64 + n * 16 + l15;
        boff[n] = 8192 + row * 32 + ((q ^ ((row >> 1) & 3)) << 3);
    }

    // stage source (per-thread, inverse-swizzled column)
    int srow = t >> 2;
    int scol = ((t & 3) ^ ((t >> 3) & 3)) * 8;
    const unsigned short* Asrc = A + (size_t)(row0 + srow) * K + scol;
    // virtual B rows: vr -> BT row (vr>>5)*dout + c0 + (vr&31)
    int br0 = (srow >> 5) * dout + c0 + (srow & 31);            // vr = srow
    int br1 = ((srow + 128) >> 5) * dout + c0 + (srow & 31);    // vr = srow+128
    const unsigned short* Bsrc0 = BT + (size_t)br0 * K + scol;
    const unsigned short* Bsrc1 = BT + (size_t)br1 * K + scol;
    int wdst = wid * 512;                            // wave-uniform dest term

    f32x4 acc[8][4];
    #pragma unroll
    for (int m = 0; m < 8; ++m)
        #pragma unroll
        for (int n = 0; n < 4; ++n) acc[m][n] = (f32x4){0.f, 0.f, 0.f, 0.f};

    // ---- prologue: stage slots 0, 1 ----
    #pragma unroll
    for (int S = 0; S < 2; ++S) {
        gload_lds16(Asrc + S * 32,                   &lds[S * 16384 + wdst]);
        gload_lds16(Asrc + (size_t)128 * K + S * 32, &lds[S * 16384 + 4096 + wdst]);
        gload_lds16(Bsrc0 + S * 32,                  &lds[S * 16384 + 8192 + wdst]);
        gload_lds16(Bsrc1 + S * 32,                  &lds[S * 16384 + 12288 + wdst]);
    }

    for (int s = 0; s < nkt; s += 2) {               // nkt is even (18 or 32)
        int sbA = (s & 3) << 14;
        int sbB = ((s + 1) & 3) << 14;
        bool st = (s + 2) < nkt;

        VM0; SB0;                                    // own loads for s,s+1 landed
        BAR;                                         // all waves' loads published
        if (st) {
            int rbA = ((s + 2) & 3) << 14;
            int rbB = ((s + 3) & 3) << 14;
            int koA = (s + 2) << 5;
            int koB = (s + 3) << 5;
            gload_lds16(Asrc + koA,                   &lds[rbA + wdst]);
            gload_lds16(Asrc + (size_t)128 * K + koA, &lds[rbA + 4096 + wdst]);
            gload_lds16(Bsrc0 + koA,                  &lds[rbA + 8192 + wdst]);
            gload_lds16(Bsrc1 + koA,                  &lds[rbA + 12288 + wdst]);
            gload_lds16(Asrc + koB,                   &lds[rbB + wdst]);
            gload_lds16(Asrc + (size_t)128 * K + koB, &lds[rbB + 4096 + wdst]);
            gload_lds16(Bsrc0 + koB,                  &lds[rbB + 8192 + wdst]);
            gload_lds16(Bsrc1 + koB,                  &lds[rbB + 12288 + wdst]);
        }
        SB0;

        // ---- slot s ----
        {
            bf16x8 bfrg[4], afr[8];
            #pragma unroll
            for (int n = 0; n < 4; ++n)
                bfrg[n] = *(const bf16x8*)(&lds[sbA + boff[n]]);
            #pragma unroll
            for (int m = 0; m < 8; ++m)
                afr[m] = *(const bf16x8*)(&lds[sbA + aoff[m]]);
            __builtin_amdgcn_s_setprio(1);
            #pragma unroll
            for (int m = 0; m < 8; ++m)
                #pragma unroll
                for (int n = 0; n < 4; ++n)
                    acc[m][n] = __builtin_amdgcn_mfma_f32_16x16x32_bf16(bfrg[n], afr[m], acc[m][n], 0, 0, 0);
            __builtin_amdgcn_s_setprio(0);
        }
        // ---- slot s+1 ----
        {
            bf16x8 bfrg[4], afr[8];
            #pragma unroll
            for (int n = 0; n < 4; ++n)
                bfrg[n] = *(const bf16x8*)(&lds[sbB + boff[n]]);
            #pragma unroll
            for (int m = 0; m < 8; ++m)
                afr[m] = *(const bf16x8*)(&lds[sbB + aoff[m]]);
            __builtin_amdgcn_s_setprio(1);
            #pragma unroll
            for (int m = 0; m < 8; ++m)
                #pragma unroll
                for (int n = 0; n < 4; ++n)
                    acc[m][n] = __builtin_amdgcn_mfma_f32_16x16x32_bf16(bfrg[n], afr[m], acc[m][n], 0, 0, 0);
            __builtin_amdgcn_s_setprio(0);
        }
        SB0;
    }

    // ======== epilogue phase 1: per-wave expert mix -> LDS fp32 partials ===
    // acc[m][n][r]: row = row0 + wm*128 + m*16 + l15;
    //               vc  = wn*64 + n*16 + q*4 + r; e = 2wn + (n>>1);
    //               j   = (n&1)*16 + q*4 + r.
    float* plds = (float*)lds;                       // 8 regions x [128][32] f32
    __syncthreads();                                 // ring fully consumed
    {
        int e0 = 2 * wn, e1 = e0 + 1;
        f32x4 b0h[2], b1h[2];
        #pragma unroll
        for (int h = 0; h < 2; ++h) {
            float4 u0 = *(const float4*)(bias + e0 * dout + c0 + h * 16 + q * 4);
            float4 u1 = *(const float4*)(bias + e1 * dout + c0 + h * 16 + q * 4);
            b0h[h] = (f32x4){u0.x, u0.y, u0.z, u0.w};
            b1h[h] = (f32x4){u1.x, u1.y, u1.z, u1.w};
        }
        float* preg = plds + (wid << 12);
        #pragma unroll
        for (int m = 0; m < 8; ++m) {
            int grow = row0 + wm * 128 + m * 16 + l15;
            float c8 = coeffs[(size_t)grow * 8 + e0];
            float c9 = coeffs[(size_t)grow * 8 + e1];
            #pragma unroll
            for (int h = 0; h < 2; ++h) {
                f32x4 z0 = acc[m][h];
                f32x4 z1 = acc[m][h + 2];
                f32x4 p;
                #pragma unroll
                for (int r = 0; r < 4; ++r)
                    p[r] = c8 * (z0[r] + b0h[h][r]) + c9 * (z1[r] + b1h[h][r]);
                int row = m * 16 + l15;
                int slot = (h * 4 + q) ^ (row & 7);
                *(f32x4*)(preg + row * 32 + (slot << 2)) = p;
            }
        }
    }
    __syncthreads();

    // ======== epilogue phase 2: sum 4 wn-partials, act, store ==============
    {
        int r2 = t >> 1;                             // tile row 0..255
        int ch = t & 1;                              // col half (16 cols)
        int wmr = r2 >> 7;
        int rr = r2 & 127;
        int sw = rr & 7;
        size_t obase = (size_t)(row0 + r2) * dout + c0 + ch * 16;
        #pragma unroll
        for (int sl = 0; sl < 4; ++sl) {
            int L = ch * 4 + sl;
            int phys = L ^ sw;
            f32x4 sum = (f32x4){0.f, 0.f, 0.f, 0.f};
            #pragma unroll
            for (int w2 = 0; w2 < 4; ++w2) {
                const f32x4 v = *(const f32x4*)(plds + (((wmr << 2) + w2) << 12) + rr * 32 + (phys << 2));
                sum[0] += v[0]; sum[1] += v[1]; sum[2] += v[2]; sum[3] += v[3];
            }
            if (DO_ELU) {
                #pragma unroll
                for (int r = 0; r < 4; ++r)
                    sum[r] = sum[r] > 0.f ? sum[r] : (__expf(sum[r]) - 1.f);
            }
            if (OUT_F32) {
                float4 o = {sum[0], sum[1], sum[2], sum[3]};
                *(float4*)((float*)Out + obase + sl * 4) = o;
            } else {
                ushort4 o;
                o.x = f2bf(sum[0]); o.y = f2bf(sum[1]);
                o.z = f2bf(sum[2]); o.w = f2bf(sum[3]);
                *(ushort4*)((unsigned short*)Out + obase + sl * 4) = o;
            }
        }
    }
}

// ---------------------------------------------------------------------------
extern "C" void kernel_launch(void* const* d_in, const int* in_sizes, int n_in,
                              void* d_out, int out_size, void* d_ws, size_t ws_size,
                              hipStream_t stream) {
    const float* motion  = (const float*)d_in[0];
    const float* command = (const float*)d_in[1];
    const float* g_w1 = (const float*)d_in[2];
    const float* g_b1 = (const float*)d_in[3];
    const float* g_w2 = (const float*)d_in[4];
    const float* g_b2 = (const float*)d_in[5];
    const float* g_w3 = (const float*)d_in[6];
    const float* g_b3 = (const float*)d_in[7];
    const float* w[6]  = {(const float*)d_in[8],  (const float*)d_in[10],
                          (const float*)d_in[12], (const float*)d_in[14],
                          (const float*)d_in[16], (const float*)d_in[18]};
    const float* bb[6] = {(const float*)d_in[9],  (const float*)d_in[11],
                          (const float*)d_in[13], (const float*)d_in[15],
                          (const float*)d_in[17], (const float*)d_in[19]};

    char* ws = (char*)d_ws;
    unsigned short* xc0  = (unsigned short*)ws;                 //  9,437,184
    unsigned short* actA = (unsigned short*)(ws + 9437184);     // 16,777,216
    unsigned short* actB = (unsigned short*)(ws + 26214400);    // 16,777,216
    float* coeffs        = (float*)(ws + 42991616);             //    262,144
    unsigned short* wT   = (unsigned short*)(ws + 43253760);    // 16,777,216

    // 1. concat + convert input
    concat_cvt<<<4608, 256, 0, stream>>>(motion, command, xc0);

    // 2. gating network
    transpose_cvt<<<144, 256, 0, stream>>>(g_w1, wT, 576, 1024, 144);
    gemm_bf16<true><<<512, 256, 0, stream>>>(xc0, wT, g_b1, actA, 1024, 576, 576);
    transpose_cvt<<<256, 256, 0, stream>>>(g_w2, wT, 1024, 1024, 256);
    gemm_bf16<true><<<512, 256, 0, stream>>>(actA, wT, g_b2, actB, 1024, 1024, 1024);
    gating_kernel<<<2048, 256, 0, stream>>>(actB, g_w3, g_b3, coeffs);

    // 3. MoE layer 0: K=576 (nkt=18), dout=1024 -> actA
    transpose_cvt<<<1152, 256, 0, stream>>>(w[0], wT, 576, 1024, 144);
    gemm_fused<true, false><<<1024, 512, 0, stream>>>(
        xc0, wT, coeffs, bb[0], actA, 576, 1024);

    // 4. MoE layers 1..4: K=1024 (nkt=32), dout=1024, ping-pong actA/actB
    unsigned short* bufs[2] = {actA, actB};
    for (int l = 1; l <= 4; ++l) {
        unsigned short* in  = bufs[(l + 1) & 1];
        unsigned short* out = bufs[l & 1];
        transpose_cvt<<<2048, 256, 0, stream>>>(w[l], wT, 1024, 1024, 256);
        gemm_fused<true, false><<<1024, 512, 0, stream>>>(
            in, wT, coeffs, bb[l], out, 1024, 1024);
    }

    // 5. MoE layer 5: K=1024, dout=512, fp32 out
    transpose_cvt<<<1024, 256, 0, stream>>>(w[5], wT, 1024, 512, 128);
    gemm_fused<false, true><<<512, 512, 0, stream>>>(
        actA, wT, coeffs, bb[5], d_out, 1024, 512);
}